// Round 2
// baseline (162.805 us; speedup 1.0000x reference)
//
#include <hip/hip_runtime.h>

#define BATCH 4096
#define CLEN  8192
#define COEF  0.1f
#define NT    256

// One block per row. Each block computes
//   row_out[b] = inv_norm(t_b) * sum_i |i - t_b| * exp(x[b,i])
// then the last-arriving block reduces the 4096 partials (fixed order ->
// bitwise-deterministic) and writes out[0] = 0.1 * total.
__global__ __launch_bounds__(NT) void dfal_fused_kernel(
    const float* __restrict__ in,
    const int*   __restrict__ target,
    float*       __restrict__ row_out,
    unsigned int* __restrict__ counter,
    float*       __restrict__ out)
{
    const int b   = blockIdx.x;
    const int tid = threadIdx.x;

    const long long t = (long long)target[b];
    // Exact sum of squared distances sum_{i=0}^{C-1} (i-t)^2, closed form.
    const long long m  = (long long)(CLEN - 1) - t;
    const long long ss = t * (t + 1) * (2 * t + 1) / 6
                       + m * (m + 1) * (2 * m + 1) / 6;
    const float inv_norm = (t == 0) ? 0.0f : (float)(1.0 / sqrt((double)ss));

    const float4* __restrict__ in4 = (const float4*)(in + (size_t)b * CLEN);
    const float tf = (float)t;

    // Issue all 8 loads (32 VGPRs) before any compute -> 8 in flight/wave.
    float4 x[8];
#pragma unroll
    for (int k = 0; k < 8; ++k) x[k] = in4[tid + k * NT];

    float acc = 0.0f;
#pragma unroll
    for (int k = 0; k < 8; ++k) {
        const float i0 = (float)(4 * (tid + k * NT));
        acc = fmaf(fabsf(i0        - tf), __expf(x[k].x), acc);
        acc = fmaf(fabsf(i0 + 1.0f - tf), __expf(x[k].y), acc);
        acc = fmaf(fabsf(i0 + 2.0f - tf), __expf(x[k].z), acc);
        acc = fmaf(fabsf(i0 + 3.0f - tf), __expf(x[k].w), acc);
    }

    // Wave (64-lane) reduction, then cross-wave via LDS.
#pragma unroll
    for (int off = 32; off; off >>= 1) acc += __shfl_down(acc, off, 64);

    __shared__ float wsum[NT / 64];
    __shared__ bool  is_last;
    if ((tid & 63) == 0) wsum[tid >> 6] = acc;
    __syncthreads();

    if (tid == 0) {
        float s = wsum[0] + wsum[1] + wsum[2] + wsum[3];
        row_out[b] = s * inv_norm;
        __threadfence();                       // partial visible device-wide
        unsigned int old = atomicAdd(counter, 1u);
        is_last = (old == BATCH - 1);
    }
    __syncthreads();
    if (!is_last) return;

    // Last block: all 4095 other partials are visible (their fence ordered
    // the write before the counter increment we observed).
    __threadfence();

    float racc = 0.0f;
#pragma unroll
    for (int i = tid; i < BATCH; i += NT) racc += row_out[i];
#pragma unroll
    for (int off = 32; off; off >>= 1) racc += __shfl_down(racc, off, 64);
    if ((tid & 63) == 0) wsum[tid >> 6] = racc;
    __syncthreads();
    if (tid == 0) out[0] = (wsum[0] + wsum[1] + wsum[2] + wsum[3]) * COEF;
}

extern "C" void kernel_launch(void* const* d_in, const int* in_sizes, int n_in,
                              void* d_out, int out_size, void* d_ws, size_t ws_size,
                              hipStream_t stream) {
    const float* input  = (const float*)d_in[0];
    const int*   target = (const int*)d_in[1];
    float*        out      = (float*)d_out;
    float*        row_part = (float*)d_ws;                    // BATCH floats
    unsigned int* counter  = (unsigned int*)((char*)d_ws + BATCH * sizeof(float));

    // Workspace is poisoned (0xAA) once and never re-poisoned: zero the
    // arrival counter every call, on-stream (graph-capture-legal).
    hipMemsetAsync(counter, 0, sizeof(unsigned int), stream);

    dfal_fused_kernel<<<BATCH, NT, 0, stream>>>(input, target, row_part, counter, out);
}

// Round 3
// 68.529 us; speedup vs baseline: 2.3757x; 2.3757x over previous
//
#include <hip/hip_runtime.h>

#define BATCH 4096
#define CLEN  8192
#define COEF  0.1f
#define NT    256

// Fixed-point packing for the single-atomic cross-block reduce:
//   bits [0,44):  sum of round(partial * 2^20)  (max ~5.4e11, 32x headroom)
//   bits [44,..): arrival count (each block adds 1<<44)
#define FIX_SCALE 1048576.0f   // 2^20
#define CNT_SHIFT 44
#define VAL_MASK  ((1ULL << CNT_SHIFT) - 1ULL)

// One block per row. partial_b = inv_norm(t_b) * sum_i |i - t_b| * exp(x[b,i]).
// Cross-block combine via ONE packed integer atomic: no __threadfence, no
// second kernel. Integer adds commute exactly -> bitwise-deterministic.
__global__ __launch_bounds__(NT) void dfal_fused2_kernel(
    const float* __restrict__ in,
    const int*   __restrict__ target,
    unsigned long long* __restrict__ acc64,
    float*       __restrict__ out)
{
    const int b   = blockIdx.x;
    const int tid = threadIdx.x;

    const long long t = (long long)target[b];
    // Exact sum of squared distances sum_{i=0}^{C-1} (i-t)^2, closed form.
    const long long m  = (long long)(CLEN - 1) - t;
    const long long ss = t * (t + 1) * (2 * t + 1) / 6
                       + m * (m + 1) * (2 * m + 1) / 6;
    const float inv_norm = (t == 0) ? 0.0f : (float)(1.0 / sqrt((double)ss));

    const float4* __restrict__ in4 = (const float4*)(in + (size_t)b * CLEN);
    const float tf = (float)t;

    // Round-1 loop form (proven ~25 us).
    float acc = 0.0f;
#pragma unroll
    for (int j = tid; j < CLEN / 4; j += NT) {
        const float4 x = in4[j];
        const float i0 = (float)(4 * j);
        acc = fmaf(fabsf(i0        - tf), __expf(x.x), acc);
        acc = fmaf(fabsf(i0 + 1.0f - tf), __expf(x.y), acc);
        acc = fmaf(fabsf(i0 + 2.0f - tf), __expf(x.z), acc);
        acc = fmaf(fabsf(i0 + 3.0f - tf), __expf(x.w), acc);
    }

    // Wave (64-lane) reduction, then cross-wave via LDS.
#pragma unroll
    for (int off = 32; off; off >>= 1) acc += __shfl_down(acc, off, 64);

    __shared__ float wsum[NT / 64];
    if ((tid & 63) == 0) wsum[tid >> 6] = acc;
    __syncthreads();

    if (tid == 0) {
        const float s = (wsum[0] + wsum[1] + wsum[2] + wsum[3]) * inv_norm;
        const unsigned long long contrib =
            (unsigned long long)llrintf(s * FIX_SCALE);
        const unsigned long long old =
            atomicAdd(acc64, (1ULL << CNT_SHIFT) | contrib);
        if ((old >> CNT_SHIFT) == (unsigned long long)(BATCH - 1)) {
            // This add completed the count: old's value field + our contrib
            // is the full sum. No memory re-read, no fence.
            const unsigned long long total = (old & VAL_MASK) + contrib;
            out[0] = (float)((double)total * (double)COEF / (double)FIX_SCALE);
        }
    }
}

extern "C" void kernel_launch(void* const* d_in, const int* in_sizes, int n_in,
                              void* d_out, int out_size, void* d_ws, size_t ws_size,
                              hipStream_t stream) {
    const float* input  = (const float*)d_in[0];
    const int*   target = (const int*)d_in[1];
    float* out = (float*)d_out;
    unsigned long long* acc64 = (unsigned long long*)d_ws;

    // ws is poisoned 0xAA once and never re-poisoned: zero the packed
    // accumulator every call, on-stream (graph-capture-legal).
    hipMemsetAsync(acc64, 0, sizeof(unsigned long long), stream);

    dfal_fused2_kernel<<<BATCH, NT, 0, stream>>>(input, target, acc64, out);
}